// Round 21
// baseline (36.964 us; speedup 1.0000x reference)
//
#include <hip/hip_runtime.h>

// CTC batch cost — producer/consumer with COALESCED row staging.
// 4 waves/block (1 item): w0 = fwd chain consumer, w1 = bwd chain consumer
// (R17 math verbatim: f32 prob domain, per-lane pow2 scale, absmax 0.0),
// w2 = fwd producer, w3 = bwd producer.
// Producers stage whole 512B rows via global_load_lds WIDTH=16 (1KB = 2 rows
// per instruction, sequential addresses; 8 instr per 16-step group) into a
// [2][4][16][128] LDS ring. Consumers gather praw[j] = ring[dir][s][j][lab]
// with cheap ds_reads. Publication: counted inline-asm vmcnt (8 instr/group,
// 3 groups in flight) + relaxed LDS flags — no barriers in the loop.

constexpr int Bc = 512, Tc = 512, Cc = 128, Lc = 48;
constexpr float FEPS = 1e-7f;
constexpr float FNEG = -1e30f;
constexpr float LN2F = 0.69314718055994530942f;
constexpr int CDEAD = -(1 << 28);
constexpr int NG = 16;      // 16-step groups per direction
constexpr int RD = 4;       // ring depth (groups)

#define DPP_WAVE_SHR1 0x138
#define DPP_WAVE_SHL1 0x130
#define WG __HIP_MEMORY_SCOPE_WORKGROUP

__device__ __forceinline__ float dppf_shr1(float x) {
    return __int_as_float(__builtin_amdgcn_update_dpp(
        0, __float_as_int(x), DPP_WAVE_SHR1, 0xF, 0xF, false));
}
__device__ __forceinline__ float dppf_shl1(float x) {
    return __int_as_float(__builtin_amdgcn_update_dpp(
        0, __float_as_int(x), DPP_WAVE_SHL1, 0xF, 0xF, false));
}
__device__ __forceinline__ int dppi_shr1_self(int c) {
    return __builtin_amdgcn_update_dpp(c, c, DPP_WAVE_SHR1, 0xF, 0xF, false);
}
__device__ __forceinline__ int dppi_shl1_self(int c) {
    return __builtin_amdgcn_update_dpp(c, c, DPP_WAVE_SHL1, 0xF, 0xF, false);
}
__device__ __forceinline__ float lae2(float a, float b) {
    float m = fmaxf(a, b);
    float d = fabsf(a - b);
    return m + __log2f(1.0f + __builtin_amdgcn_exp2f(-d));
}
__device__ __forceinline__ float rd63f(float v) {
    return __uint_as_float((unsigned)
        __builtin_amdgcn_readlane(__float_as_uint(v), 63));
}

typedef const __attribute__((address_space(1))) void* gptr_t;
typedef __attribute__((address_space(3))) void* lptr_t;
__device__ __forceinline__ void gload16(const float* g, float* l) {
    __builtin_amdgcn_global_load_lds((gptr_t)g, (lptr_t)l, 16, 0, 0);
}

__global__ __launch_bounds__(256)
void ctc_pc_kernel(const int* __restrict__ y_true,
                   const float* __restrict__ y_pred,
                   float* __restrict__ out) {
    const int b = blockIdx.x;
    const int tid = threadIdx.x;
    const int lane = tid & 63;
    const int wid = tid >> 6;          // 0,1 consumers; 2,3 producers

    __shared__ float ring[2][RD][16][Cc];   // 64 KB
    __shared__ int ready[2], done[2];
    __shared__ float sblo[64], sbhi[64];
    __shared__ int sbc[64];

    const float* yb = y_pred + (size_t)b * Tc * Cc;
    const int lab = (lane < Lc) ? y_true[b * Lc + lane] : (Cc - 1);

    if (tid == 0) { ready[0] = ready[1] = 0; done[0] = done[1] = 0; }
    __syncthreads();   // flags visible before pipeline starts

    if (wid >= 2) {
        // ------------------------- producer (dir = wid-2) -------------------
        const int d = wid - 2;
        const int jbase = lane >> 5;            // sub-row within the 1KB pair
        const int col = (lane & 31) * 4;        // 16B-aligned column
        auto issue_group = [&](int g) {         // 8 coalesced 1KB gll instrs
            float* lb = &ring[d][g & (RD - 1)][0][0];
            #pragma unroll
            for (int i = 0; i < 8; ++i) {
                const int step = 2 * i + jbase;
                const int t = d ? (511 - (g * 16 + step)) : (g * 16 + step);
                gload16(yb + (size_t)t * Cc + col, lb + i * 2 * Cc);
            }
        };
        auto publish = [&](int v) {
            __builtin_amdgcn_sched_barrier(0);
            if (lane == 0)
                __hip_atomic_store(&ready[d], v, __ATOMIC_RELAXED, WG);
            __builtin_amdgcn_sched_barrier(0);
        };
        issue_group(0); issue_group(1); issue_group(2);
        #pragma unroll 1
        for (int g = 0; g < NG - 3; ++g) {
            // slot (g+3)&3 held group g-1; wait until consumer finished it
            while (__hip_atomic_load(&done[d], __ATOMIC_RELAXED, WG) < g)
                __builtin_amdgcn_s_sleep(1);
            issue_group(g + 3);
            asm volatile("s_waitcnt vmcnt(24)" ::: "memory");  // group g landed
            publish(g + 1);
        }
        asm volatile("s_waitcnt vmcnt(16)" ::: "memory");
        publish(NG - 2);
        asm volatile("s_waitcnt vmcnt(8)" ::: "memory");
        publish(NG - 1);
        asm volatile("s_waitcnt vmcnt(0)" ::: "memory");
        publish(NG);
    } else {
        // ------------------------- consumer (dir = wid) ---------------------
        const int dir = wid;
        const int labm1 = __builtin_amdgcn_ds_bpermute(((lane + 63) & 63) << 2, lab);
        const bool skip = (lab != (Cc - 1)) && (lab != labm1);
        const bool validhi = (lane < Lc);
        const bool lane0 = (lane == 0);

        float lo = 0.0f, hi = 0.0f;
        int c = CDEAD;

        auto renorm = [&]() {
            float mx = fmaxf(lo, hi);
            int e = (int)((__float_as_uint(mx) >> 23) & 0xFF) - 127;
            e = (mx > 0.0f) ? e : 0;
            lo = ldexpf(lo, -e);
            hi = ldexpf(hi, -e);
            c += e;
        };

        float praw[16], pbf[16], phf[16];

        if (dir == 1) {   // beta_511 init
            lo = (lane == 48) ? 1.0f : 0.0f;
            hi = (lane == 47) ? 1.0f : 0.0f;
            c  = (lane == 47 || lane == 48) ? 0 : CDEAD;
        }

        #pragma unroll 1
        for (int g = 0; g < NG; ++g) {
            while (__hip_atomic_load(&ready[dir], __ATOMIC_RELAXED, WG) < g + 1)
                __builtin_amdgcn_s_sleep(1);
            __builtin_amdgcn_sched_barrier(0);
            #pragma unroll
            for (int j = 0; j < 16; ++j)
                praw[j] = ring[dir][g & (RD - 1)][j][lab];
            #pragma unroll
            for (int j = 0; j < 16; ++j) {
                pbf[j] = rd63f(praw[j]) + FEPS;
                phf[j] = validhi ? (praw[j] + FEPS) : 0.0f;
            }
            if (dir == 0) {
                int j0 = 0;
                if (g == 0) {   // init at t=0
                    lo = lane0 ? pbf[0] : 0.0f;
                    hi = lane0 ? phf[0] : 0.0f;
                    c  = lane0 ? 0 : CDEAD;
                    j0 = 1;
                }
                #pragma unroll
                for (int j = 0; j < 16; ++j) {
                    if (j < j0) continue;
                    float sh  = dppf_shr1(hi);
                    int   cm1 = dppi_shr1_self(c);
                    bool  own_dead = (lo == 0.0f) && (hi == 0.0f);
                    int   m  = own_dead ? cm1 : ((c > cm1) ? c : cm1);
                    float lov = ldexpf(lo, c - m);
                    float hiv = ldexpf(hi, c - m);
                    float shv = ldexpf(sh, cm1 - m);
                    float a3  = skip ? shv : 0.0f;
                    lo = (lov + shv) * pbf[j];
                    hi = (hiv + lov + a3) * phf[j];
                    c = m;
                    if (j == 7 || j == 15) renorm();
                }
            } else {
                #pragma unroll
                for (int j = 0; j < 16; ++j) {
                    float qlo = lo * pbf[j];
                    float qhi = hi * phf[j];
                    float u   = qlo + (skip ? qhi : 0.0f);
                    float un  = dppf_shl1(u);
                    int   cp1 = dppi_shl1_self(c);
                    bool  own_dead = (qlo == 0.0f) && (qhi == 0.0f);
                    int   m  = own_dead ? cp1 : ((c > cp1) ? c : cp1);
                    lo = ldexpf(qlo + qhi, c - m);
                    hi = ldexpf(qhi, c - m) + ldexpf(un, cp1 - m);
                    c = m;
                    if (j == 7 || j == 15) renorm();
                }
            }
            __builtin_amdgcn_sched_barrier(0);
            if (lane == 0)
                __hip_atomic_store(&done[dir], g + 1, __ATOMIC_RELAXED, WG);
        }

        if (dir == 1) {
            sblo[lane] = lo;
            sbhi[lane] = hi;
            sbc[lane]  = c;
        }
        __syncthreads();
        if (dir == 0) {
            float blo = sblo[lane], bhi = sbhi[lane];
            float ctot = (float)(c + sbc[lane]);
            float plo = lo * blo;
            float phi = hi * bhi;
            float yl = (plo > 0.0f) ? (__log2f(plo) + ctot) : FNEG;
            float yh = (phi > 0.0f) ? (__log2f(phi) + ctot) : FNEG;
            float v = lae2(yl, yh);
            #pragma unroll
            for (int mk = 1; mk < 64; mk <<= 1)
                v = lae2(v, __shfl_xor(v, mk, 64));
            if (lane0) out[b] = -(v * LN2F);
        }
        return;
    }
    __syncthreads();   // producers join the consumers' final barrier
}

extern "C" void kernel_launch(void* const* d_in, const int* in_sizes, int n_in,
                              void* d_out, int out_size, void* d_ws, size_t ws_size,
                              hipStream_t stream) {
    const int* y_true = (const int*)d_in[0];
    const float* y_pred = (const float*)d_in[1];
    float* out = (float*)d_out;
    hipLaunchKernelGGL(ctc_pc_kernel, dim3(Bc), dim3(256), 0, stream,
                       y_true, y_pred, out);
}

// Round 22
// 36.455 us; speedup vs baseline: 1.0139x; 1.0139x over previous
//
#include <hip/hip_runtime.h>

// CTC batch cost, forward-backward split, f32 probability domain, PER-LANE
// power-of-2 scaling (R17 math verbatim, absmax 0.0).
// Round-22 change: TWO ITEMS PER WAVE-PAIR. 256 blocks (1/CU) x 2 waves;
// wave 0 = forward chains of items (2b, 2b+1) interleaved in registers,
// wave 1 = backward chains. The two chains are independent streams in one
// basic block -> the scheduler fills chain A's dependent-latency stalls with
// chain B's instructions, halving the per-item exposed-chain cost measured
// in rounds 18-21 (mem ~20.5us invariant + ~8.5us exposed chain).

constexpr int Bc = 512, Tc = 512, Cc = 128, Lc = 48;
constexpr float FEPS = 1e-7f;
constexpr float FNEG = -1e30f;
constexpr float LN2F = 0.69314718055994530942f;
constexpr int CDEAD = -(1 << 28);

#define DPP_WAVE_SHR1 0x138
#define DPP_WAVE_SHL1 0x130

__device__ __forceinline__ float dppf_shr1(float x) {
    return __int_as_float(__builtin_amdgcn_update_dpp(
        0, __float_as_int(x), DPP_WAVE_SHR1, 0xF, 0xF, false));
}
__device__ __forceinline__ float dppf_shl1(float x) {
    return __int_as_float(__builtin_amdgcn_update_dpp(
        0, __float_as_int(x), DPP_WAVE_SHL1, 0xF, 0xF, false));
}
__device__ __forceinline__ int dppi_shr1_self(int c) {
    return __builtin_amdgcn_update_dpp(c, c, DPP_WAVE_SHR1, 0xF, 0xF, false);
}
__device__ __forceinline__ int dppi_shl1_self(int c) {
    return __builtin_amdgcn_update_dpp(c, c, DPP_WAVE_SHL1, 0xF, 0xF, false);
}
__device__ __forceinline__ float lae2(float a, float b) {
    float m = fmaxf(a, b);
    float d = fabsf(a - b);
    return m + __log2f(1.0f + __builtin_amdgcn_exp2f(-d));
}
__device__ __forceinline__ float rd63f(float v) {
    return __uint_as_float((unsigned)
        __builtin_amdgcn_readlane(__float_as_uint(v), 63));
}

__global__ __launch_bounds__(128)
void ctc_fb2_kernel(const int* __restrict__ y_true,
                    const float* __restrict__ y_pred,
                    float* __restrict__ out) {
    const int bA = blockIdx.x * 2;
    const int bB = bA + 1;
    const int lane = threadIdx.x & 63;
    const int wave = threadIdx.x >> 6;

    const float* ybA = y_pred + (size_t)bA * Tc * Cc;
    const float* ybB = y_pred + (size_t)bB * Tc * Cc;

    const int labA = (lane < Lc) ? y_true[bA * Lc + lane] : (Cc - 1);
    const int labB = (lane < Lc) ? y_true[bB * Lc + lane] : (Cc - 1);
    const int pa = ((lane + 63) & 63) << 2;
    const int labm1A = __builtin_amdgcn_ds_bpermute(pa, labA);
    const int labm1B = __builtin_amdgcn_ds_bpermute(pa, labB);
    const bool skipA = (labA != (Cc - 1)) && (labA != labm1A);
    const bool skipB = (labB != (Cc - 1)) && (labB != labm1B);
    const bool validhi = (lane < Lc);
    const bool lane0 = (lane == 0);

    __shared__ float sblo[2][64], sbhi[2][64];
    __shared__ int sbc[2][64];

    float loA = 0.0f, hiA = 0.0f, loB = 0.0f, hiB = 0.0f;
    int cA = CDEAD, cB = CDEAD;

    auto renorm2 = [&]() {   // lane-local, both items (independent -> ILP)
        float mxA = fmaxf(loA, hiA);
        float mxB = fmaxf(loB, hiB);
        int eA = (int)((__float_as_uint(mxA) >> 23) & 0xFF) - 127;
        int eB = (int)((__float_as_uint(mxB) >> 23) & 0xFF) - 127;
        eA = (mxA > 0.0f) ? eA : 0;
        eB = (mxB > 0.0f) ? eB : 0;
        loA = ldexpf(loA, -eA); hiA = ldexpf(hiA, -eA);
        loB = ldexpf(loB, -eB); hiB = ldexpf(hiB, -eB);
        cA += eA; cB += eB;
    };

    float prA[16], prB[16], pbA[16], phA[16], pbB[16], phB[16];
    auto batch2 = [&]() {
        #pragma unroll
        for (int j = 0; j < 16; ++j) {
            pbA[j] = rd63f(prA[j]) + FEPS;
            phA[j] = validhi ? (prA[j] + FEPS) : 0.0f;
            pbB[j] = rd63f(prB[j]) + FEPS;
            phB[j] = validhi ? (prB[j] + FEPS) : 0.0f;
        }
    };

    if (wave == 0) {
        // ------------- forward chains for items A and B (t = 0..255) --------
        auto step2 = [&](int j) {
            float shA = dppf_shr1(hiA);
            float shB = dppf_shr1(hiB);
            int cm1A = dppi_shr1_self(cA);
            int cm1B = dppi_shr1_self(cB);
            bool dA = (loA == 0.0f) && (hiA == 0.0f);
            bool dB = (loB == 0.0f) && (hiB == 0.0f);
            int mA = dA ? cm1A : ((cA > cm1A) ? cA : cm1A);
            int mB = dB ? cm1B : ((cB > cm1B) ? cB : cm1B);
            float lovA = ldexpf(loA, cA - mA), lovB = ldexpf(loB, cB - mB);
            float hivA = ldexpf(hiA, cA - mA), hivB = ldexpf(hiB, cB - mB);
            float shvA = ldexpf(shA, cm1A - mA), shvB = ldexpf(shB, cm1B - mB);
            float a3A = skipA ? shvA : 0.0f, a3B = skipB ? shvB : 0.0f;
            loA = (lovA + shvA) * pbA[j];
            hiA = (hivA + lovA + a3A) * phA[j];
            loB = (lovB + shvB) * pbB[j];
            hiB = (hivB + lovB + a3B) * phB[j];
            cA = mA; cB = mB;
        };
        #pragma unroll
        for (int j = 0; j < 16; ++j) {
            prA[j] = ybA[j * Cc + labA];
            prB[j] = ybB[j * Cc + labB];
        }
        {   // group 0 (t=0..15), init at t=0
            batch2();
            const float* ybnA = ybA + (size_t)16 * Cc + labA;
            const float* ybnB = ybB + (size_t)16 * Cc + labB;
            #pragma unroll
            for (int j = 0; j < 16; ++j) {
                prA[j] = ybnA[(size_t)j * Cc];
                prB[j] = ybnB[(size_t)j * Cc];
            }
            loA = lane0 ? pbA[0] : 0.0f;
            hiA = lane0 ? phA[0] : 0.0f;
            loB = lane0 ? pbB[0] : 0.0f;
            hiB = lane0 ? phB[0] : 0.0f;
            cA = lane0 ? 0 : CDEAD;
            cB = lane0 ? 0 : CDEAD;
            #pragma unroll
            for (int j = 1; j < 16; ++j) {
                step2(j);
                if (j == 7 || j == 15) renorm2();
            }
        }
        #pragma unroll 1
        for (int g = 1; g < 16; ++g) {
            batch2();
            if (g < 15) {
                const float* ybnA = ybA + (size_t)((g + 1) * 16) * Cc + labA;
                const float* ybnB = ybB + (size_t)((g + 1) * 16) * Cc + labB;
                #pragma unroll
                for (int j = 0; j < 16; ++j) {
                    prA[j] = ybnA[(size_t)j * Cc];
                    prB[j] = ybnB[(size_t)j * Cc];
                }
            }
            #pragma unroll
            for (int j = 0; j < 16; ++j) {
                step2(j);
                if (j == 7 || j == 15) renorm2();
            }
        }
    } else {
        // ------------- backward chains for items A and B (t = 511..256) -----
        auto step2 = [&](int j) {
            float qloA = loA * pbA[j];
            float qhiA = hiA * phA[j];
            float qloB = loB * pbB[j];
            float qhiB = hiB * phB[j];
            float uA = qloA + (skipA ? qhiA : 0.0f);
            float uB = qloB + (skipB ? qhiB : 0.0f);
            float unA = dppf_shl1(uA);
            float unB = dppf_shl1(uB);
            int cp1A = dppi_shl1_self(cA);
            int cp1B = dppi_shl1_self(cB);
            bool dA = (qloA == 0.0f) && (qhiA == 0.0f);
            bool dB = (qloB == 0.0f) && (qhiB == 0.0f);
            int mA = dA ? cp1A : ((cA > cp1A) ? cA : cp1A);
            int mB = dB ? cp1B : ((cB > cp1B) ? cB : cp1B);
            loA = ldexpf(qloA + qhiA, cA - mA);
            hiA = ldexpf(qhiA, cA - mA) + ldexpf(unA, cp1A - mA);
            loB = ldexpf(qloB + qhiB, cB - mB);
            hiB = ldexpf(qhiB, cB - mB) + ldexpf(unB, cp1B - mB);
            cA = mA; cB = mB;
        };
        loA = (lane == 48) ? 1.0f : 0.0f;
        hiA = (lane == 47) ? 1.0f : 0.0f;
        loB = (lane == 48) ? 1.0f : 0.0f;
        hiB = (lane == 47) ? 1.0f : 0.0f;
        cA = (lane == 47 || lane == 48) ? 0 : CDEAD;
        cB = cA;
        #pragma unroll
        for (int j = 0; j < 16; ++j) {
            prA[j] = ybA[(size_t)(511 - j) * Cc + labA];
            prB[j] = ybB[(size_t)(511 - j) * Cc + labB];
        }
        #pragma unroll 1
        for (int g = 0; g < 16; ++g) {
            batch2();
            if (g < 15) {
                const int t0 = 511 - (g + 1) * 16;
                #pragma unroll
                for (int j = 0; j < 16; ++j) {
                    prA[j] = ybA[(size_t)(t0 - j) * Cc + labA];
                    prB[j] = ybB[(size_t)(t0 - j) * Cc + labB];
                }
            }
            #pragma unroll
            for (int j = 0; j < 16; ++j) {
                step2(j);
                if (j == 7 || j == 15) renorm2();
            }
        }
        sblo[0][lane] = loA; sbhi[0][lane] = hiA; sbc[0][lane] = cA;
        sblo[1][lane] = loB; sbhi[1][lane] = hiB; sbc[1][lane] = cB;
    }

    __syncthreads();

    if (wave == 0) {
        // item A
        {
            float ctot = (float)(cA + sbc[0][lane]);
            float plo = loA * sblo[0][lane];
            float phi = hiA * sbhi[0][lane];
            float yl = (plo > 0.0f) ? (__log2f(plo) + ctot) : FNEG;
            float yh = (phi > 0.0f) ? (__log2f(phi) + ctot) : FNEG;
            float v = lae2(yl, yh);
            #pragma unroll
            for (int mk = 1; mk < 64; mk <<= 1)
                v = lae2(v, __shfl_xor(v, mk, 64));
            if (lane0) out[bA] = -(v * LN2F);
        }
        // item B
        {
            float ctot = (float)(cB + sbc[1][lane]);
            float plo = loB * sblo[1][lane];
            float phi = hiB * sbhi[1][lane];
            float yl = (plo > 0.0f) ? (__log2f(plo) + ctot) : FNEG;
            float yh = (phi > 0.0f) ? (__log2f(phi) + ctot) : FNEG;
            float v = lae2(yl, yh);
            #pragma unroll
            for (int mk = 1; mk < 64; mk <<= 1)
                v = lae2(v, __shfl_xor(v, mk, 64));
            if (lane0) out[bB] = -(v * LN2F);
        }
    }
}

extern "C" void kernel_launch(void* const* d_in, const int* in_sizes, int n_in,
                              void* d_out, int out_size, void* d_ws, size_t ws_size,
                              hipStream_t stream) {
    const int* y_true = (const int*)d_in[0];
    const float* y_pred = (const float*)d_in[1];
    float* out = (float*)d_out;
    hipLaunchKernelGGL(ctc_fb2_kernel, dim3(Bc / 2), dim3(128), 0, stream,
                       y_true, y_pred, out);
}

// Round 23
// 32.478 us; speedup vs baseline: 1.1381x; 1.1225x over previous
//
#include <hip/hip_runtime.h>

// CTC batch cost, forward-backward split, f32 probability domain, PER-LANE
// power-of-2 scaling (R17 math verbatim, absmax 0.0).
// Round-23 change: KILL THE SCATTER. Per row (512B = 128 classes), ONE
// coalesced dwordx2 load (lane l holds classes {2l,2l+1}) instead of a
// 64-address scattered gather (~190cyc TA, measured rounds 18-22 as the
// invariant ~20us memory floor). praw redistribution via 2x ds_bpermute
// (source lane = lab>>1, component = lab&1) + select, batched off-chain.
// Blank prob = lane63's .y (readlane). Ping-pong rA/rB register row buffers
// issued TWO groups ahead (~1.2us cover >> load latency).
// Wave 0: forward alpha_255 (t=0..255). Wave 1: backward beta_255 (t=511..256).
// loglik = log2(sum_s alpha_255[s]*beta_255[s]) + ca + cb.

constexpr int Bc = 512, Tc = 512, Cc = 128, Lc = 48;
constexpr float FEPS = 1e-7f;
constexpr float FNEG = -1e30f;
constexpr float LN2F = 0.69314718055994530942f;
constexpr int CDEAD = -(1 << 28);

#define DPP_WAVE_SHR1 0x138
#define DPP_WAVE_SHL1 0x130

__device__ __forceinline__ float dppf_shr1(float x) {
    return __int_as_float(__builtin_amdgcn_update_dpp(
        0, __float_as_int(x), DPP_WAVE_SHR1, 0xF, 0xF, false));
}
__device__ __forceinline__ float dppf_shl1(float x) {
    return __int_as_float(__builtin_amdgcn_update_dpp(
        0, __float_as_int(x), DPP_WAVE_SHL1, 0xF, 0xF, false));
}
__device__ __forceinline__ int dppi_shr1_self(int c) {
    return __builtin_amdgcn_update_dpp(c, c, DPP_WAVE_SHR1, 0xF, 0xF, false);
}
__device__ __forceinline__ int dppi_shl1_self(int c) {
    return __builtin_amdgcn_update_dpp(c, c, DPP_WAVE_SHL1, 0xF, 0xF, false);
}
__device__ __forceinline__ float lae2(float a, float b) {
    float m = fmaxf(a, b);
    float d = fabsf(a - b);
    return m + __log2f(1.0f + __builtin_amdgcn_exp2f(-d));
}
__device__ __forceinline__ float rd63f(float v) {
    return __uint_as_float((unsigned)
        __builtin_amdgcn_readlane(__float_as_uint(v), 63));
}
__device__ __forceinline__ float bperm_f(int byteaddr, float v) {
    return __int_as_float(__builtin_amdgcn_ds_bpermute(byteaddr, __float_as_int(v)));
}

__global__ __launch_bounds__(128)
void ctc_fb_kernel(const int* __restrict__ y_true,
                   const float* __restrict__ y_pred,
                   float* __restrict__ out) {
    const int b = blockIdx.x;
    const int lane = threadIdx.x & 63;
    const int wave = threadIdx.x >> 6;

    const float* yb = y_pred + (size_t)b * Tc * Cc;

    const int lab = (lane < Lc) ? y_true[b * Lc + lane] : (Cc - 1);
    const int labm1 = __builtin_amdgcn_ds_bpermute(((lane + 63) & 63) << 2, lab);
    const bool skip  = (lab != (Cc - 1)) && (lab != labm1);
    const bool validhi = (lane < Lc);
    const bool lane0 = (lane == 0);
    const int rowaddr = (lab >> 1) << 2;   // bpermute byte addr: source lane lab>>1
    const bool odd = (lab & 1) != 0;

    __shared__ float sblo[64], sbhi[64];
    __shared__ int sbc[64];

    float lo = 0.0f, hi = 0.0f;
    int c = CDEAD;

    auto renorm = [&]() {   // lane-local, every 8 steps (R17 cadence)
        float mx = fmaxf(lo, hi);
        int e = (int)((__float_as_uint(mx) >> 23) & 0xFF) - 127;
        e = (mx > 0.0f) ? e : 0;
        lo = ldexpf(lo, -e);
        hi = ldexpf(hi, -e);
        c += e;
    };

    float2 rA[16], rB[16];     // ping-pong row buffers (coalesced dwordx2 loads)
    float pbf[16], phf[16];

    auto batch = [&](float2 (&buf)[16]) {   // rows -> per-lane probs, off-chain
        #pragma unroll
        for (int j = 0; j < 16; ++j) {
            float v0 = bperm_f(rowaddr, buf[j].x);   // row[lab & ~1]
            float v1 = bperm_f(rowaddr, buf[j].y);   // row[lab | 1]
            float praw = odd ? v1 : v0;              // row[lab]
            pbf[j] = rd63f(buf[j].y) + FEPS;         // row[127] = blank
            phf[j] = validhi ? (praw + FEPS) : 0.0f;
        }
    };

    if (wave == 0) {
        // -------- forward: alpha_255, consume p_0..p_255 --------
        auto step = [&](int j) {
            float sh  = dppf_shr1(hi);
            int   cm1 = dppi_shr1_self(c);
            bool  own_dead = (lo == 0.0f) && (hi == 0.0f);
            int   m  = own_dead ? cm1 : ((c > cm1) ? c : cm1);
            float lov = ldexpf(lo, c - m);
            float hiv = ldexpf(hi, c - m);
            float shv = ldexpf(sh, cm1 - m);
            float a3  = skip ? shv : 0.0f;
            lo = (lov + shv) * pbf[j];
            hi = (hiv + lov + a3) * phf[j];
            c = m;
        };
        auto steps16 = [&]() {
            #pragma unroll
            for (int j = 0; j < 16; ++j) {
                step(j);
                if (j == 7 || j == 15) renorm();
            }
        };
        auto issue = [&](float2 (&buf)[16], int g) {   // 16 coalesced dwordx2
            const float* base = yb + (size_t)(g * 16) * Cc + lane * 2;
            #pragma unroll
            for (int j = 0; j < 16; ++j)
                buf[j] = *reinterpret_cast<const float2*>(base + (size_t)j * Cc);
        };
        issue(rA, 0); issue(rB, 1);
        // group 0 (from rA), init at t=0
        batch(rA); issue(rA, 2);
        lo = lane0 ? pbf[0] : 0.0f;
        hi = lane0 ? phf[0] : 0.0f;
        c  = lane0 ? 0 : CDEAD;
        #pragma unroll
        for (int j = 1; j < 16; ++j) {
            step(j);
            if (j == 7 || j == 15) renorm();
        }
        batch(rB); issue(rB, 3); steps16();
        #pragma unroll 1
        for (int k = 1; k < 8; ++k) {
            batch(rA); if (2 * k + 2 < 16) issue(rA, 2 * k + 2); steps16();
            batch(rB); if (2 * k + 3 < 16) issue(rB, 2 * k + 3); steps16();
        }
    } else {
        // -------- backward: beta_255, consume p_511..p_256 --------
        auto step = [&](int j) {
            float qlo = lo * pbf[j];
            float qhi = hi * phf[j];
            float u   = qlo + (skip ? qhi : 0.0f);
            float un  = dppf_shl1(u);
            int   cp1 = dppi_shl1_self(c);
            bool  own_dead = (qlo == 0.0f) && (qhi == 0.0f);
            int   m  = own_dead ? cp1 : ((c > cp1) ? c : cp1);
            lo = ldexpf(qlo + qhi, c - m);
            hi = ldexpf(qhi, c - m) + ldexpf(un, cp1 - m);
            c = m;
        };
        auto steps16 = [&]() {
            #pragma unroll
            for (int j = 0; j < 16; ++j) {
                step(j);
                if (j == 7 || j == 15) renorm();
            }
        };
        auto issue = [&](float2 (&buf)[16], int g) {
            const int t0 = 511 - g * 16;
            const float* base = yb + lane * 2;
            #pragma unroll
            for (int j = 0; j < 16; ++j)
                buf[j] = *reinterpret_cast<const float2*>(base + (size_t)(t0 - j) * Cc);
        };
        lo = (lane == 48) ? 1.0f : 0.0f;
        hi = (lane == 47) ? 1.0f : 0.0f;
        c  = (lane == 47 || lane == 48) ? 0 : CDEAD;
        issue(rA, 0); issue(rB, 1);
        batch(rA); issue(rA, 2); steps16();
        batch(rB); issue(rB, 3); steps16();
        #pragma unroll 1
        for (int k = 1; k < 8; ++k) {
            batch(rA); if (2 * k + 2 < 16) issue(rA, 2 * k + 2); steps16();
            batch(rB); if (2 * k + 3 < 16) issue(rB, 2 * k + 3); steps16();
        }
        sblo[lane] = lo;
        sbhi[lane] = hi;
        sbc[lane]  = c;
    }

    __syncthreads();

    if (wave == 0) {
        float blo = sblo[lane], bhi = sbhi[lane];
        float ctot = (float)(c + sbc[lane]);
        float plo = lo * blo;
        float phi = hi * bhi;
        float yl = (plo > 0.0f) ? (__log2f(plo) + ctot) : FNEG;
        float yh = (phi > 0.0f) ? (__log2f(phi) + ctot) : FNEG;
        float v = lae2(yl, yh);
        #pragma unroll
        for (int mk = 1; mk < 64; mk <<= 1)
            v = lae2(v, __shfl_xor(v, mk, 64));
        if (lane0) out[b] = -(v * LN2F);
    }
}

extern "C" void kernel_launch(void* const* d_in, const int* in_sizes, int n_in,
                              void* d_out, int out_size, void* d_ws, size_t ws_size,
                              hipStream_t stream) {
    const int* y_true = (const int*)d_in[0];
    const float* y_pred = (const float*)d_in[1];
    float* out = (float*)d_out;
    hipLaunchKernelGGL(ctc_fb_kernel, dim3(Bc), dim3(128), 0, stream,
                       y_true, y_pred, out);
}

// Round 24
// 29.014 us; speedup vs baseline: 1.2740x; 1.1194x over previous
//
#include <hip/hip_runtime.h>

// CTC batch cost, forward-backward split, f64 probability domain, wave-uniform
// power-of-2 renorm every 32 steps (bit-identical to round 11; absmax 0.0).
// BEST VERIFIED VARIANT (round 16, 29.0us) — restored as final state.
//  - per-16-step batch phase precomputes pb64[16]/ph64[16] (readlane, +DEPS in
//    f64, validhi mask, cvt) OFF the serial chain, dense and independent;
//  - chain keeps only: dpp64 + select + 3 add_f64 + 2 mul_f64 per step;
//  - bwd chain uses nb = shl1(qlo + (skip ? qhi : 0)) == skipN?(qlo_n+qhi_n):qlo_n
//    (skipN_l == skip_{l+1}), halving bwd DPPs;
//  - renorm reduces the integer biased exponent (int shuffles, same e).
// Wave 0: forward alpha_255 (t=0..255). Wave 1: backward beta_255 (t=511..256).
// loglik = log2(sum_s alpha_255[s]*beta_255[s]) + ca + cb.
//
// Measured component breakdown (round 18 probes): gather stream alone = 20.6us
// sustained (3.25 TB/s for this pattern, invariant across 5 transport schemes);
// serial chain ~9us; best achieved overlap leaves total at ~29us.

constexpr int Bc = 512, Tc = 512, Cc = 128, Lc = 48;
constexpr double DEPS = 1e-7;
constexpr float FNEG = -1e30f;
constexpr float LN2F = 0.69314718055994530942f;

#define DPP_WAVE_SHR1 0x138
#define DPP_WAVE_SHL1 0x130

__device__ __forceinline__ double dpp64_shr1(double x) {
    // lane l <- lane l-1; lane 0 <- 0.0
    long long u = __double_as_longlong(x);
    int a = __builtin_amdgcn_update_dpp(0, (int)u,         DPP_WAVE_SHR1, 0xF, 0xF, false);
    int b = __builtin_amdgcn_update_dpp(0, (int)(u >> 32), DPP_WAVE_SHR1, 0xF, 0xF, false);
    return __longlong_as_double(((long long)b << 32) | (unsigned int)a);
}
__device__ __forceinline__ double dpp64_shl1(double x) {
    // lane l <- lane l+1; lane 63 <- 0.0
    long long u = __double_as_longlong(x);
    int a = __builtin_amdgcn_update_dpp(0, (int)u,         DPP_WAVE_SHL1, 0xF, 0xF, false);
    int b = __builtin_amdgcn_update_dpp(0, (int)(u >> 32), DPP_WAVE_SHL1, 0xF, 0xF, false);
    return __longlong_as_double(((long long)b << 32) | (unsigned int)a);
}

__device__ __forceinline__ float lae2(float a, float b) {  // final reduce only
    float m = fmaxf(a, b);
    float d = fabsf(a - b);
    return m + __log2f(1.0f + __builtin_amdgcn_exp2f(-d));
}
__device__ __forceinline__ float rd63f(float v) {
    return __uint_as_float((unsigned)
        __builtin_amdgcn_readlane(__float_as_uint(v), 63));
}
__device__ __forceinline__ float log2d(double x) {
    if (!(x > 0.0)) return FNEG;
    long long u = __double_as_longlong(x);
    int e = (int)((u >> 52) & 0x7FF);
    if (e == 0) return FNEG;
    double m = __longlong_as_double((u & 0x000FFFFFFFFFFFFFLL) | 0x3FF0000000000000LL);
    return __log2f((float)m) + (float)(e - 1023);
}

__global__ __launch_bounds__(128)
void ctc_fb_kernel(const int* __restrict__ y_true,
                   const float* __restrict__ y_pred,
                   float* __restrict__ out) {
    const int b = blockIdx.x;
    const int lane = threadIdx.x & 63;
    const int wave = threadIdx.x >> 6;

    const float* yb = y_pred + (size_t)b * Tc * Cc;

    const int lab = (lane < Lc) ? y_true[b * Lc + lane] : (Cc - 1);
    const int labm1 = __builtin_amdgcn_ds_bpermute(((lane + 63) & 63) << 2, lab);
    const bool skip  = (lab != (Cc - 1)) && (lab != labm1);   // into 2l+1 from 2l-1
    const bool validhi = (lane < Lc);
    const bool lane0 = (lane == 0);

    __shared__ double sblo[64], sbhi[64];
    __shared__ int sbc[64];

    double lo = 0.0, hi = 0.0;
    int c = 0;   // wave-uniform log2 scale (exact integer)

    auto renorm = [&]() {
        double mx = fmax(lo, hi);
        int eb = (int)((__double_as_longlong(mx) >> 52) & 0x7FF);
        #pragma unroll
        for (int mk = 1; mk < 64; mk <<= 1)
            eb = max(eb, __shfl_xor(eb, mk, 64));
        int e = eb - 1023;
        double sc = __longlong_as_double((long long)(1023 - e) << 52);  // exact 2^-e
        lo *= sc; hi *= sc;
        c += e;
    };

    float praw[16];
    double pb64[16], ph64[16];

    auto batch = [&]() {   // off-chain: per-step probs in f64
        #pragma unroll
        for (int j = 0; j < 16; ++j) {
            pb64[j] = (double)rd63f(praw[j]) + DEPS;
            ph64[j] = validhi ? ((double)praw[j] + DEPS) : 0.0;
        }
    };

    if (wave == 0) {
        // -------- forward: alpha_255, consume p_0..p_255 --------
        auto step = [&](int j) {
            double sh = dpp64_shr1(hi);            // alpha[2l-1]
            double a3 = skip ? sh : 0.0;
            double nlo = (lo + sh) * pb64[j];      // even state (blank)
            double nhi = ((hi + lo) + a3) * ph64[j];  // odd state (label)
            lo = nlo; hi = nhi;
        };
        #pragma unroll
        for (int j = 0; j < 16; ++j) praw[j] = yb[j * Cc + lab];
        {   // group 0 (t=0..15), init at t=0
            batch();
            const float* ybn = yb + (size_t)16 * Cc + lab;
            #pragma unroll
            for (int j = 0; j < 16; ++j) praw[j] = ybn[(size_t)j * Cc];
            lo = lane0 ? pb64[0] : 0.0;   // state 0 = blank
            hi = lane0 ? ph64[0] : 0.0;   // state 1 = label[0]
            #pragma unroll
            for (int j = 1; j < 16; ++j) step(j);
        }
        #pragma unroll 1
        for (int g = 1; g < 16; ++g) {
            batch();
            if (g < 15) {
                const float* ybn = yb + (size_t)((g + 1) * 16) * Cc + lab;
                #pragma unroll
                for (int j = 0; j < 16; ++j) praw[j] = ybn[(size_t)j * Cc];
            }
            #pragma unroll
            for (int j = 0; j < 16; ++j) step(j);
            if (g & 1) renorm();          // every 32 steps
        }
    } else {
        // -------- backward: beta_255, consume p_511..p_256 --------
        // q[s] = beta_{t+1}[s] * p_{t+1}[s]
        // beta_t[2l]   = q[2l] + q[2l+1]
        // beta_t[2l+1] = q[2l+1] + shl1( q[2l] + (skip ? q[2l+1] : 0) )
        auto step = [&](int j) {
            double qlo = lo * pb64[j];             // q[2l]
            double qhi = hi * ph64[j];             // q[2l+1]
            double u  = qlo + (skip ? qhi : 0.0);  // lane l+1's contribution source
            double nb = dpp64_shl1(u);
            lo = qlo + qhi;
            hi = qhi + nb;
        };
        lo = (lane == 48) ? 1.0 : 0.0;    // beta_511: state 96
        hi = (lane == 47) ? 1.0 : 0.0;    // beta_511: state 95
        #pragma unroll
        for (int j = 0; j < 16; ++j) praw[j] = yb[(size_t)(511 - j) * Cc + lab];
        #pragma unroll 1
        for (int g = 0; g < 16; ++g) {
            batch();
            if (g < 15) {
                const float* ybn = yb + lab;
                const int t0 = 511 - (g + 1) * 16;
                #pragma unroll
                for (int j = 0; j < 16; ++j) praw[j] = ybn[(size_t)(t0 - j) * Cc];
            }
            #pragma unroll
            for (int j = 0; j < 16; ++j) step(j);
            if (g & 1) renorm();          // every 32 steps
        }
        sblo[lane] = lo;
        sbhi[lane] = hi;
        sbc[lane]  = c;
    }

    __syncthreads();

    if (wave == 0) {
        // loglik = log2( sum_s alpha_255[s]*beta_255[s] ) + ca + cb
        double plo = lo * sblo[lane];
        double phi = hi * sbhi[lane];
        float ctot = (float)(c + sbc[lane]);
        float yl = log2d(plo) + ctot;
        float yh = log2d(phi) + ctot;
        float v = lae2(yl, yh);
        #pragma unroll
        for (int mk = 1; mk < 64; mk <<= 1)
            v = lae2(v, __shfl_xor(v, mk, 64));
        if (lane0) out[b] = -(v * LN2F);
    }
}

extern "C" void kernel_launch(void* const* d_in, const int* in_sizes, int n_in,
                              void* d_out, int out_size, void* d_ws, size_t ws_size,
                              hipStream_t stream) {
    const int* y_true = (const int*)d_in[0];
    const float* y_pred = (const float*)d_in[1];
    float* out = (float*)d_out;
    hipLaunchKernelGGL(ctc_fb_kernel, dim3(Bc), dim3(128), 0, stream,
                       y_true, y_pred, out);
}